// Round 2
// baseline (482.889 us; speedup 1.0000x reference)
//
#include <hip/hip_runtime.h>
#include <hip/hip_bf16.h>

typedef __hip_bfloat16 bf16;
typedef __attribute__((ext_vector_type(8))) short bf16x8;   // 8 bf16 = 4 VGPR
typedef __attribute__((ext_vector_type(4))) float f32x4;

#define N_NODES   131072
#define N_GRAPHS  4096
#define FIN       256
#define FH        512
#define NPAD      176     // 164 padded to 11*16
#define NREAL     164

// ---------- workspace layout (bytes) ----------
#define OFF_XB     0UL                        // bf16 131072x256   = 67,108,864
#define OFF_XEND   67108864UL                 // f32  4096x256     =  4,194,304
#define OFF_XENDB  71303168UL                 // bf16 4096x256     =  2,097,152
#define OFF_W1A    73400320UL                 // bf16 512x256      =    262,144
#define OFF_BCAT   73662464UL                 // bf16 1024x256     =    524,288
#define OFF_WXB    74186752UL                 // bf16 176x512      =    180,224
#define OFF_CCAT   74366976UL                 // f32  4096x1024    = 16,777,216
#define OFF_H      91144192UL                 // bf16 131072x512   = 134,217,728
#define OFF_STATS  225361920UL                // f32  4x512        = 8,192  (memset 0)
#define OFF_COEF   225370112UL                // f32  4x512
#define OFF_XXE    225378304UL                // f32  4096
// total ~215 MB

__device__ __forceinline__ void gld_lds16(const void* g, void* l) {
  // async global->LDS, 16B/lane; LDS dest = wave-uniform base + lane*16
  __builtin_amdgcn_global_load_lds(
      (const __attribute__((address_space(1))) void*)g,
      (__attribute__((address_space(3))) void*)l, 16, 0, 0);
}

__device__ __forceinline__ float bf2f(unsigned short u) {
  unsigned int x = ((unsigned int)u) << 16; float f;
  __builtin_memcpy(&f, &x, 4); return f;
}
__device__ __forceinline__ unsigned short f2bf(float f) {
  bf16 h = __float2bfloat16(f); unsigned short u;
  __builtin_memcpy(&u, &h, 2); return u;
}

// ---------- K0: weight casts ----------
__global__ __launch_bounds__(256) void k_wcast(
    const float* __restrict__ W_h, const float* __restrict__ W_ht,
    const float* __restrict__ W_x,
    bf16* __restrict__ W1a, bf16* __restrict__ Bcat, bf16* __restrict__ Wxb)
{
  int i = blockIdx.x * 256 + threadIdx.x;            // grid 1024 -> 262144
  if (i < 512 * 512) {
    int of = i >> 9, ic = i & 511;
    float v = W_h[i];
    if (ic < 256) W1a[of * 256 + ic] = __float2bfloat16(v);
    else          Bcat[of * 256 + (ic - 256)] = __float2bfloat16(v);
  }
  if (i < 512 * 256) Bcat[512 * 256 + i] = __float2bfloat16(W_ht[i]);
  if (i < NPAD * 512) {
    int n = i >> 9;
    Wxb[i] = (n < NREAL) ? __float2bfloat16(W_x[i]) : __float2bfloat16(0.f);
  }
}

// ---------- K1: X -> bf16 + per-graph mean ----------
// NOTE: harness converts int64 inputs to int32 — NX must be read as int!
__global__ __launch_bounds__(256) void k_xend(
    const float* __restrict__ X, const int* __restrict__ NX,
    bf16* __restrict__ Xb, float* __restrict__ X_end, bf16* __restrict__ X_endb)
{
  int g = blockIdx.x;                 // 4096
  int f = threadIdx.x;                // 256
  float s = 0.f;
  long base = (long)g * 32 * FIN + f;
  #pragma unroll 4
  for (int n = 0; n < 32; ++n) {
    float v = X[base + (long)n * FIN];
    s += v;
    Xb[base + (long)n * FIN] = __float2bfloat16(v);
  }
  float m = s / (float)NX[g];
  X_end[g * FIN + f] = m;
  X_endb[g * FIN + f] = __float2bfloat16(m);
}

// ---------- generic 128x128 bf16 TN GEMM (m97 structure), K multiple of 32 ----
// MODE 0: C f32 (ldc)           MODE 1: H bf16 (ld 512) with per-graph add term
template <int MODE>
__global__ __launch_bounds__(256, 2) void gemm_tn(
    const bf16* __restrict__ A, int lda,
    const bf16* __restrict__ B, int ldb, int K,
    const float* __restrict__ Cterm, int ldct,
    float* __restrict__ Cout, int ldc,
    bf16* __restrict__ Hout, int nblk)
{
  const int bid = blockIdx.x;
  const int blkM = bid / nblk, blkN = bid % nblk;
  const int tid = threadIdx.x;
  const int w = tid >> 6, lane = tid & 63;
  const int wm = w >> 1, wn = w & 1;

  __shared__ __align__(16) bf16 lA[128 * 32];
  __shared__ __align__(16) bf16 lB[128 * 32];

  f32x4 acc[4][4] = {};

  const int rS = lane >> 2;            // staging row within 16-row chunk
  const int cS = (lane & 3) * 8;       // staging k-offset (elements)
  const long baseA = (long)blkM * 128;
  const long baseB = (long)blkN * 128;

  for (int kk = 0; kk < K; kk += 32) {
    #pragma unroll
    for (int c = 0; c < 2; ++c) {
      int chunk = 2 * w + c;           // 8 chunks of 16 rows
      gld_lds16(A + (baseA + chunk * 16 + rS) * lda + kk + cS, &lA[chunk * 16 * 32]);
      gld_lds16(B + (baseB + chunk * 16 + rS) * ldb + kk + cS, &lB[chunk * 16 * 32]);
    }
    __syncthreads();
    bf16x8 a8[4], b8[4];
    #pragma unroll
    for (int t = 0; t < 4; ++t) {
      a8[t] = *(const bf16x8*)&lA[(wm * 64 + t * 16 + (lane & 15)) * 32 + (lane >> 4) * 8];
      b8[t] = *(const bf16x8*)&lB[(wn * 64 + t * 16 + (lane & 15)) * 32 + (lane >> 4) * 8];
    }
    #pragma unroll
    for (int tm = 0; tm < 4; ++tm)
      #pragma unroll
      for (int tn = 0; tn < 4; ++tn)
        acc[tm][tn] = __builtin_amdgcn_mfma_f32_16x16x32_bf16(a8[tm], b8[tn], acc[tm][tn], 0, 0, 0);
    __syncthreads();
  }

  const int rowq = (lane >> 4) * 4;    // C/D: col=lane&15, row=(lane>>4)*4+reg
  const int coll = lane & 15;
  #pragma unroll
  for (int tm = 0; tm < 4; ++tm)
    #pragma unroll
    for (int tn = 0; tn < 4; ++tn)
      #pragma unroll
      for (int r = 0; r < 4; ++r) {
        long row = baseA + wm * 64 + tm * 16 + rowq + r;
        int col = (int)baseB + wn * 64 + tn * 16 + coll;
        if (MODE == 0) {
          Cout[row * ldc + col] = acc[tm][tn][r];
        } else {
          int g = (int)(row >> 5);
          float h = acc[tm][tn][r] + Cterm[(long)g * ldct + col];
          Hout[row * FH + col] = __float2bfloat16(h);
        }
      }
}

// ---------- column stats (sum, sumsq) ----------
__global__ __launch_bounds__(256) void k_stats_main(
    const bf16* __restrict__ H, float* __restrict__ s1, float* __restrict__ s2)
{
  long r0 = (long)blockIdx.x * 128;    // grid 1024
  int tid = threadIdx.x;
  #pragma unroll
  for (int cc = 0; cc < 2; ++cc) {
    int c = tid + cc * 256;
    float a = 0.f, b = 0.f;
    for (int r = 0; r < 128; ++r) {
      float v = bf2f(*(const unsigned short*)&H[(r0 + r) * FH + c]);
      a += v; b += v * v;
    }
    atomicAdd(&s1[c], a); atomicAdd(&s2[c], b);
  }
}

__global__ __launch_bounds__(256) void k_stats_end(
    const float* __restrict__ Ccat, float* __restrict__ s1, float* __restrict__ s2)
{
  long r0 = (long)blockIdx.x * 64;     // grid 64
  int tid = threadIdx.x;
  #pragma unroll
  for (int cc = 0; cc < 2; ++cc) {
    int c = tid + cc * 256;
    float a = 0.f, b = 0.f;
    for (int r = 0; r < 64; ++r) {
      float v = Ccat[(r0 + r) * 1024 + 512 + c];
      a += v; b += v * v;
    }
    atomicAdd(&s1[c], a); atomicAdd(&s2[c], b);
  }
}

// ---------- BN coeff finalize: a = g*rsqrt(var+eps), c = b - mean*a ----------
__global__ __launch_bounds__(256) void k_finalize(
    const float* __restrict__ s1, const float* __restrict__ s2,
    const float* __restrict__ gam, const float* __restrict__ bet,
    float invN, float* __restrict__ a_s, float* __restrict__ c_s)
{
  int c = blockIdx.x * 256 + threadIdx.x;   // grid 2
  if (c < FH) {
    float mean = s1[c] * invN;
    float var = s2[c] * invN - mean * mean;
    float a = gam[c] / sqrtf(var + 1e-5f);
    a_s[c] = a;
    c_s[c] = bet[c] - mean * a;
  }
}

// ---------- end path: X_x_end[g] = exp(dot(relu(a*Hend+c), W_xt) + b_xt) -----
__global__ __launch_bounds__(256) void k_xxend(
    const float* __restrict__ Ccat, const float* __restrict__ at,
    const float* __restrict__ ct, const float* __restrict__ Wxt,
    const float* __restrict__ bxt, float* __restrict__ Xxe)
{
  int w = threadIdx.x >> 6, lane = threadIdx.x & 63;
  int g = blockIdx.x * 4 + w;          // grid 1024
  const float* h = Ccat + (long)g * 1024 + 512;
  float acc = 0.f;
  #pragma unroll
  for (int i = 0; i < 8; ++i) {
    int j = lane + i * 64;
    float x = fmaxf(at[j] * h[j] + ct[j], 0.f);
    acc += x * Wxt[j];
  }
  #pragma unroll
  for (int off = 32; off; off >>= 1) acc += __shfl_xor(acc, off);
  if (lane == 0) Xxe[g] = expf(acc + bxt[0]);
}

// ---------- in-place H -> bf16(relu(a*H+c)) ----------
__global__ __launch_bounds__(256) void k_transform(
    bf16* __restrict__ H, const float* __restrict__ a_s, const float* __restrict__ c_s)
{
  long i = ((long)blockIdx.x * 256 + threadIdx.x) * 8;   // grid 32768
  int c0 = (int)(i & 511);
  uint4 d = *(const uint4*)((const char*)H + i * 2);
  unsigned short* u = (unsigned short*)&d;
  #pragma unroll
  for (int t = 0; t < 8; ++t) {
    float v = bf2f(u[t]);
    v = fmaxf(a_s[c0 + t] * v + c_s[c0 + t], 0.f);
    u[t] = f2bf(v);
  }
  *(uint4*)((char*)H + i * 2) = d;
}

// ---------- GEMM2 + fused exp/graph-softmax epilogue ----------
// block = 128 rows (4 graphs), all 176 padded cols; wave w owns graph blk*4+w
__global__ __launch_bounds__(256, 2) void gemm2_softmax(
    const bf16* __restrict__ A2, const bf16* __restrict__ Wxb,
    const float* __restrict__ b_x, const float* __restrict__ Xxe,
    float* __restrict__ outA, float* __restrict__ outC, float* __restrict__ outE)
{
  const int blk = blockIdx.x;          // 1024
  const int tid = threadIdx.x;
  const int w = tid >> 6, lane = tid & 63;

  __shared__ __align__(16) bf16 lA[128 * 32];
  __shared__ __align__(16) bf16 lB[NPAD * 32];

  f32x4 acc[2][11] = {};
  const int rS = lane >> 2;
  const int cS = (lane & 3) * 8;
  const long baseRow = (long)blk * 128;

  for (int kk = 0; kk < FH; kk += 32) {
    #pragma unroll
    for (int c = 0; c < 2; ++c) {
      int chunk = 2 * w + c;
      gld_lds16(A2 + (baseRow + chunk * 16 + rS) * FH + kk + cS, &lA[chunk * 16 * 32]);
    }
    for (int o = w; o < 11; o += 4)
      gld_lds16(Wxb + (o * 16 + rS) * FH + kk + cS, &lB[o * 16 * 32]);
    __syncthreads();

    bf16x8 a8[2], b8[11];
    #pragma unroll
    for (int t = 0; t < 2; ++t)
      a8[t] = *(const bf16x8*)&lA[(w * 32 + t * 16 + (lane & 15)) * 32 + (lane >> 4) * 8];
    #pragma unroll
    for (int t = 0; t < 11; ++t)
      b8[t] = *(const bf16x8*)&lB[(t * 16 + (lane & 15)) * 32 + (lane >> 4) * 8];
    #pragma unroll
    for (int tm = 0; tm < 2; ++tm)
      #pragma unroll
      for (int tn = 0; tn < 11; ++tn)
        acc[tm][tn] = __builtin_amdgcn_mfma_f32_16x16x32_bf16(a8[tm], b8[tn], acc[tm][tn], 0, 0, 0);
    __syncthreads();
  }

  // epilogue: exp(+b_x), per-graph sum, divide, scatter to outputs
  const int rowq = (lane >> 4) * 4;
  const int coll = lane & 15;
  const int g = blk * 4 + w;
  float psum = 0.f;
  #pragma unroll
  for (int tn = 0; tn < 11; ++tn) {
    int col = tn * 16 + coll;
    bool valid = col < NREAL;
    float bx = valid ? b_x[col] : 0.f;
    #pragma unroll
    for (int tm = 0; tm < 2; ++tm)
      #pragma unroll
      for (int r = 0; r < 4; ++r) {
        float p = valid ? expf(acc[tm][tn][r] + bx) : 0.f;
        acc[tm][tn][r] = p;
        psum += p;
      }
  }
  #pragma unroll
  for (int off = 32; off; off >>= 1) psum += __shfl_xor(psum, off);
  float Xe = Xxe[g];
  float inv = 1.0f / (psum + Xe);
  if (lane == 0) outE[g] = Xe * inv;

  #pragma unroll
  for (int tn = 0; tn < 11; ++tn) {
    int col = tn * 16 + coll;
    if (col >= NREAL) continue;
    #pragma unroll
    for (int tm = 0; tm < 2; ++tm)
      #pragma unroll
      for (int r = 0; r < 4; ++r) {
        long row = baseRow + w * 32 + tm * 16 + rowq + r;
        float v = acc[tm][tn][r] * inv;
        if (col >= 4) outA[row * 160 + (col - 4)] = v;
        else          outC[row * 4 + col] = v;
      }
  }
}

extern "C" void kernel_launch(void* const* d_in, const int* in_sizes, int n_in,
                              void* d_out, int out_size, void* d_ws, size_t ws_size,
                              hipStream_t stream)
{
  const float* X    = (const float*)d_in[0];
  const int*   NX   = (const int*)d_in[1];      // int64 in ref -> int32 in harness
  // d_in[2] = NX_rep (int32): graph id = node>>5 structurally; unused
  const float* W_h  = (const float*)d_in[3];
  const float* g_h  = (const float*)d_in[4];
  const float* b_h  = (const float*)d_in[5];
  const float* W_ht = (const float*)d_in[6];
  const float* g_ht = (const float*)d_in[7];
  const float* b_ht = (const float*)d_in[8];
  const float* W_x  = (const float*)d_in[9];
  const float* b_x  = (const float*)d_in[10];
  const float* W_xt = (const float*)d_in[11];
  const float* b_xt = (const float*)d_in[12];

  char* ws = (char*)d_ws;
  bf16*  Xb    = (bf16*)(ws + OFF_XB);
  float* X_end = (float*)(ws + OFF_XEND);
  bf16*  X_endb= (bf16*)(ws + OFF_XENDB);
  bf16*  W1a   = (bf16*)(ws + OFF_W1A);
  bf16*  Bcat  = (bf16*)(ws + OFF_BCAT);
  bf16*  Wxb   = (bf16*)(ws + OFF_WXB);
  float* Ccat  = (float*)(ws + OFF_CCAT);
  bf16*  H     = (bf16*)(ws + OFF_H);
  float* stats = (float*)(ws + OFF_STATS);
  float* s1m = stats, *s2m = stats + 512, *s1e = stats + 1024, *s2e = stats + 1536;
  float* coef  = (float*)(ws + OFF_COEF);
  float* a_s = coef, *c_s = coef + 512, *at_s = coef + 1024, *ct_s = coef + 1536;
  float* Xxe   = (float*)(ws + OFF_XXE);

  float* outA = (float*)d_out;                 // append: 131072*160
  float* outC = outA + (long)N_NODES * 160;    // connect: 131072*4
  float* outE = outC + (long)N_NODES * 4;      // end: 4096

  hipMemsetAsync(stats, 0, 4 * 512 * sizeof(float), stream);

  k_wcast<<<1024, 256, 0, stream>>>(W_h, W_ht, W_x, W1a, Bcat, Wxb);
  k_xend<<<N_GRAPHS, 256, 0, stream>>>(X, NX, Xb, X_end, X_endb);

  // [Bterm | Hend] = X_end @ [W1b; W_ht]^T : M=4096, N=1024, K=256
  gemm_tn<0><<<256, 256, 0, stream>>>(X_endb, FIN, Bcat, FIN, FIN,
                                      nullptr, 0, Ccat, 1024, nullptr, 8);
  k_stats_end<<<64, 256, 0, stream>>>(Ccat, s1e, s2e);
  k_finalize<<<2, 256, 0, stream>>>(s1e, s2e, g_ht, b_ht, 1.f / 4096.f, at_s, ct_s);
  k_xxend<<<1024, 256, 0, stream>>>(Ccat, at_s, ct_s, W_xt, b_xt, Xxe);

  // H = X @ W1a^T + Bterm[graph] : M=131072, N=512, K=256
  gemm_tn<1><<<4096, 256, 0, stream>>>(Xb, FIN, W1a, FIN, FIN,
                                       Ccat, 1024, nullptr, 0, H, 4);
  k_stats_main<<<1024, 256, 0, stream>>>(H, s1m, s2m);
  k_finalize<<<2, 256, 0, stream>>>(s1m, s2m, g_h, b_h, 1.f / 131072.f, a_s, c_s);
  k_transform<<<32768, 256, 0, stream>>>(H, a_s, c_s);

  gemm2_softmax<<<1024, 256, 0, stream>>>(H, Wxb, b_x, Xxe, outA, outC, outE);
}

// Round 3
// 427.551 us; speedup vs baseline: 1.1294x; 1.1294x over previous
//
#include <hip/hip_runtime.h>
#include <hip/hip_bf16.h>

typedef __hip_bfloat16 bf16;
typedef __attribute__((ext_vector_type(8))) short bf16x8;   // 8 bf16 = 4 VGPR
typedef __attribute__((ext_vector_type(4))) float f32x4;

#define N_NODES   131072
#define N_GRAPHS  4096
#define FIN       256
#define FH        512
#define NPAD      176     // 164 padded to 11*16
#define NREAL     164

// ---------- workspace layout (bytes) ----------
#define OFF_XENDB  0UL            // bf16 4096x256  = 2,097,152
#define OFF_W1A    2097152UL      // bf16 512x256   =   262,144
#define OFF_BCAT   2359296UL      // bf16 1024x256  =   524,288
#define OFF_WXB    2883584UL      // bf16 176x512   =   180,224
#define OFF_STATS  3063808UL      // f32  4x512     =     8,192
#define OFF_XXE    3072000UL      // f32  4096      =    16,384
#define OFF_CCAT   3088384UL      // f32  4096x1024 = 16,777,216
#define OFF_H      19865600UL     // bf16 131072x512= 134,217,728
// total ~154 MB

__device__ __forceinline__ void gld_lds16(const void* g, void* l) {
  __builtin_amdgcn_global_load_lds(
      (const __attribute__((address_space(1))) void*)g,
      (__attribute__((address_space(3))) void*)l, 16, 0, 0);
}

__device__ __forceinline__ float bf2f(unsigned short u) {
  unsigned int x = ((unsigned int)u) << 16; float f;
  __builtin_memcpy(&f, &x, 4); return f;
}
__device__ __forceinline__ unsigned short f2bf(float f) {
  bf16 h = __float2bfloat16(f); unsigned short u;
  __builtin_memcpy(&u, &h, 2); return u;
}

// ---------- K0: weight casts + zero stats ----------
__global__ __launch_bounds__(256) void k_wcast(
    const float* __restrict__ W_h, const float* __restrict__ W_ht,
    const float* __restrict__ W_x,
    bf16* __restrict__ W1a, bf16* __restrict__ Bcat, bf16* __restrict__ Wxb,
    float* __restrict__ stats)
{
  int i = blockIdx.x * 256 + threadIdx.x;            // grid 1024 -> 262144
  if (i < 2048) stats[i] = 0.f;                      // s1m,s2m,s1e,s2e
  if (i < 512 * 512) {
    int of = i >> 9, ic = i & 511;
    float v = W_h[i];
    if (ic < 256) W1a[of * 256 + ic] = __float2bfloat16(v);
    else          Bcat[of * 256 + (ic - 256)] = __float2bfloat16(v);
  }
  if (i < 512 * 256) Bcat[512 * 256 + i] = __float2bfloat16(W_ht[i]);
  if (i < NPAD * 512) {
    int n = i >> 9;
    Wxb[i] = (n < NREAL) ? __float2bfloat16(W_x[i]) : __float2bfloat16(0.f);
  }
}

// ---------- K1: per-graph mean of X (float4 loads) ----------
__global__ __launch_bounds__(256) void k_xend(
    const float* __restrict__ X, const int* __restrict__ NX,
    bf16* __restrict__ X_endb)
{
  int g = blockIdx.x;                 // 4096
  int t = threadIdx.x;
  int cg = t & 63;                    // cols cg*4..+3
  int rg = t >> 6;                    // rows rg*8..+7
  const float* Xg = X + (long)g * 32 * FIN;
  float4 s = {0.f, 0.f, 0.f, 0.f};
  #pragma unroll
  for (int r = 0; r < 8; ++r) {
    float4 v = *(const float4*)(Xg + (rg * 8 + r) * FIN + cg * 4);
    s.x += v.x; s.y += v.y; s.z += v.z; s.w += v.w;
  }
  __shared__ float4 red[256];
  red[t] = s;
  __syncthreads();
  if (t < 64) {
    float4 a = red[t], b = red[t + 64], c = red[t + 128], d = red[t + 192];
    float inv = 1.f / (float)NX[g];
    float4 m = {(a.x + b.x + c.x + d.x) * inv, (a.y + b.y + c.y + d.y) * inv,
                (a.z + b.z + c.z + d.z) * inv, (a.w + b.w + c.w + d.w) * inv};
    ushort4 u = {f2bf(m.x), f2bf(m.y), f2bf(m.z), f2bf(m.w)};
    *(ushort4*)(X_endb + (long)g * FIN + t * 4) = u;
  }
}

// ---------- GEMM0: Ccat = X_endb @ [W1b; W_ht]^T  (M=4096,N=1024,K=256) ------
// + fused column stats for cols 512..1023 (the Hend half)
__global__ __launch_bounds__(256, 2) void gemm0(
    const bf16* __restrict__ A, const bf16* __restrict__ B,
    float* __restrict__ Cout, float* __restrict__ s1e, float* __restrict__ s2e)
{
  const int bid = blockIdx.x;                 // 256
  const int blkM = bid >> 3, blkN = bid & 7;
  const int tid = threadIdx.x;
  const int w = tid >> 6, lane = tid & 63;
  const int wm = w >> 1, wn = w & 1;

  __shared__ __align__(16) bf16 lA[128 * 32];
  __shared__ __align__(16) bf16 lB[128 * 32];
  __shared__ float sred[2][2][128];

  f32x4 acc[4][4] = {};
  const int rS = lane >> 2;
  const int cS = (lane & 3) * 8;
  const long baseA = (long)blkM * 128;
  const long baseB = (long)blkN * 128;

  for (int kk = 0; kk < FIN; kk += 32) {
    #pragma unroll
    for (int c = 0; c < 2; ++c) {
      int chunk = 2 * w + c;
      gld_lds16(A + (baseA + chunk * 16 + rS) * FIN + kk + cS, &lA[chunk * 16 * 32]);
      gld_lds16(B + (baseB + chunk * 16 + rS) * FIN + kk + cS, &lB[chunk * 16 * 32]);
    }
    __syncthreads();
    bf16x8 a8[4], b8[4];
    #pragma unroll
    for (int t = 0; t < 4; ++t) {
      a8[t] = *(const bf16x8*)&lA[(wm * 64 + t * 16 + (lane & 15)) * 32 + (lane >> 4) * 8];
      b8[t] = *(const bf16x8*)&lB[(wn * 64 + t * 16 + (lane & 15)) * 32 + (lane >> 4) * 8];
    }
    #pragma unroll
    for (int tm = 0; tm < 4; ++tm)
      #pragma unroll
      for (int tn = 0; tn < 4; ++tn)
        acc[tm][tn] = __builtin_amdgcn_mfma_f32_16x16x32_bf16(a8[tm], b8[tn], acc[tm][tn], 0, 0, 0);
    __syncthreads();
  }

  const int rowq = (lane >> 4) * 4;
  const int coll = lane & 15;
  float p1[4] = {0.f, 0.f, 0.f, 0.f}, p2[4] = {0.f, 0.f, 0.f, 0.f};
  #pragma unroll
  for (int tm = 0; tm < 4; ++tm)
    #pragma unroll
    for (int tn = 0; tn < 4; ++tn)
      #pragma unroll
      for (int r = 0; r < 4; ++r) {
        long row = baseA + wm * 64 + tm * 16 + rowq + r;
        int col = (int)baseB + wn * 64 + tn * 16 + coll;
        float v = acc[tm][tn][r];
        Cout[row * 1024 + col] = v;
        p1[tn] += v; p2[tn] += v * v;
      }

  if (blkN >= 4) {
    #pragma unroll
    for (int tn = 0; tn < 4; ++tn) {
      float q1 = p1[tn], q2 = p2[tn];
      q1 += __shfl_xor(q1, 16); q1 += __shfl_xor(q1, 32);
      q2 += __shfl_xor(q2, 16); q2 += __shfl_xor(q2, 32);
      if (lane < 16) {
        sred[wm][0][wn * 64 + tn * 16 + lane] = q1;
        sred[wm][1][wn * 64 + tn * 16 + lane] = q2;
      }
    }
    __syncthreads();
    int st = tid >> 7, c = tid & 127;
    float v = sred[0][st][c] + sred[1][st][c];
    atomicAdd((st ? s2e : s1e) + (blkN - 4) * 128 + c, v);
  }
}

// ---------- K3: end path, folded finalize ----------
__global__ __launch_bounds__(256) void k_xxend(
    const float* __restrict__ Ccat, const float* __restrict__ s1e,
    const float* __restrict__ s2e, const float* __restrict__ g_ht,
    const float* __restrict__ b_ht, const float* __restrict__ Wxt,
    const float* __restrict__ bxt, float* __restrict__ Xxe)
{
  __shared__ float aL[512], cL[512];
  int tid = threadIdx.x;
  #pragma unroll
  for (int i = tid; i < 512; i += 256) {
    float mean = s1e[i] * 2.44140625e-4f;
    float var = s2e[i] * 2.44140625e-4f - mean * mean;
    float a = g_ht[i] / sqrtf(var + 1e-5f);
    aL[i] = a; cL[i] = b_ht[i] - mean * a;
  }
  __syncthreads();
  int w = tid >> 6, lane = tid & 63;
  int g = blockIdx.x * 4 + w;          // grid 1024
  const float* h = Ccat + (long)g * 1024 + 512;
  float acc = 0.f;
  #pragma unroll
  for (int i = 0; i < 8; ++i) {
    int j = lane + i * 64;
    float x = fmaxf(aL[j] * h[j] + cL[j], 0.f);
    acc += x * Wxt[j];
  }
  #pragma unroll
  for (int off = 32; off; off >>= 1) acc += __shfl_xor(acc, off);
  if (lane == 0) Xxe[g] = expf(acc + bxt[0]);
}

// ---------- GEMM1: H = bf16(X @ W1a^T + Bterm[graph]) + fused stats ----------
// M=131072, N=512, K=256; A staged from f32 X with inline bf16 cast
__global__ __launch_bounds__(256, 2) void gemm1(
    const float* __restrict__ X, const bf16* __restrict__ W1a,
    const float* __restrict__ Ccat, bf16* __restrict__ H,
    float* __restrict__ s1m, float* __restrict__ s2m)
{
  const int bid = blockIdx.x;                 // 4096
  const int blkM = bid >> 2, blkN = bid & 3;
  const int tid = threadIdx.x;
  const int w = tid >> 6, lane = tid & 63;
  const int wm = w >> 1, wn = w & 1;

  __shared__ __align__(16) bf16 lA[128 * 32];
  __shared__ __align__(16) bf16 lB[128 * 32];
  __shared__ float sred[2][2][128];

  f32x4 acc[4][4] = {};
  const int rS = lane >> 2;
  const int cS = (lane & 3) * 8;
  const long baseA = (long)blkM * 128;
  const long baseB = (long)blkN * 128;

  for (int kk = 0; kk < FIN; kk += 32) {
    #pragma unroll
    for (int c = 0; c < 2; ++c) {
      int chunk = 2 * w + c;
      gld_lds16(W1a + (baseB + chunk * 16 + rS) * FIN + kk + cS, &lB[chunk * 16 * 32]);
    }
    #pragma unroll
    for (int c = 0; c < 2; ++c) {
      int chunk = 2 * w + c;
      const float* src = X + (baseA + chunk * 16 + rS) * FIN + kk + cS;
      float4 v0 = *(const float4*)src;
      float4 v1 = *(const float4*)(src + 4);
      ushort4 u0 = {f2bf(v0.x), f2bf(v0.y), f2bf(v0.z), f2bf(v0.w)};
      ushort4 u1 = {f2bf(v1.x), f2bf(v1.y), f2bf(v1.z), f2bf(v1.w)};
      uint4 pk; __builtin_memcpy(&pk, &u0, 8); __builtin_memcpy(((char*)&pk) + 8, &u1, 8);
      *(uint4*)&lA[(chunk * 16 + rS) * 32 + cS] = pk;
    }
    __syncthreads();
    bf16x8 a8[4], b8[4];
    #pragma unroll
    for (int t = 0; t < 4; ++t) {
      a8[t] = *(const bf16x8*)&lA[(wm * 64 + t * 16 + (lane & 15)) * 32 + (lane >> 4) * 8];
      b8[t] = *(const bf16x8*)&lB[(wn * 64 + t * 16 + (lane & 15)) * 32 + (lane >> 4) * 8];
    }
    #pragma unroll
    for (int tm = 0; tm < 4; ++tm)
      #pragma unroll
      for (int tn = 0; tn < 4; ++tn)
        acc[tm][tn] = __builtin_amdgcn_mfma_f32_16x16x32_bf16(a8[tm], b8[tn], acc[tm][tn], 0, 0, 0);
    __syncthreads();
  }

  const int rowq = (lane >> 4) * 4;
  const int coll = lane & 15;
  float p1[4] = {0.f, 0.f, 0.f, 0.f}, p2[4] = {0.f, 0.f, 0.f, 0.f};
  #pragma unroll
  for (int tm = 0; tm < 4; ++tm)
    #pragma unroll
    for (int tn = 0; tn < 4; ++tn)
      #pragma unroll
      for (int r = 0; r < 4; ++r) {
        long row = baseA + wm * 64 + tm * 16 + rowq + r;
        int col = (int)baseB + wn * 64 + tn * 16 + coll;
        int g = (int)(row >> 5);
        float h = acc[tm][tn][r] + Ccat[(long)g * 1024 + col];
        H[row * FH + col] = __float2bfloat16(h);
        p1[tn] += h; p2[tn] += h * h;
      }

  #pragma unroll
  for (int tn = 0; tn < 4; ++tn) {
    float q1 = p1[tn], q2 = p2[tn];
    q1 += __shfl_xor(q1, 16); q1 += __shfl_xor(q1, 32);
    q2 += __shfl_xor(q2, 16); q2 += __shfl_xor(q2, 32);
    if (lane < 16) {
      sred[wm][0][wn * 64 + tn * 16 + lane] = q1;
      sred[wm][1][wn * 64 + tn * 16 + lane] = q2;
    }
  }
  __syncthreads();
  int st = tid >> 7, c = tid & 127;
  float v = sred[0][st][c] + sred[1][st][c];
  atomicAdd((st ? s2m : s1m) + (int)baseB + c, v);
}

// ---------- GEMM2: fused BN-finalize + relu-transform + exp/graph-softmax ----
__global__ __launch_bounds__(256, 2) void gemm2(
    const bf16* __restrict__ Hraw, const bf16* __restrict__ Wxb,
    const float* __restrict__ s1m, const float* __restrict__ s2m,
    const float* __restrict__ g_h, const float* __restrict__ b_h,
    const float* __restrict__ b_x, const float* __restrict__ Xxe,
    float* __restrict__ outA, float* __restrict__ outC, float* __restrict__ outE)
{
  const int blk = blockIdx.x;          // 1024
  const int tid = threadIdx.x;
  const int w = tid >> 6, lane = tid & 63;

  __shared__ __align__(16) bf16 lA[128 * 32];
  __shared__ __align__(16) bf16 lB[NPAD * 32];
  __shared__ float aL[512], cL[512];

  #pragma unroll
  for (int i = tid; i < 512; i += 256) {
    float mean = s1m[i] * 7.62939453125e-6f;
    float var = s2m[i] * 7.62939453125e-6f - mean * mean;
    float a = g_h[i] / sqrtf(var + 1e-5f);
    aL[i] = a; cL[i] = b_h[i] - mean * a;
  }
  __syncthreads();

  f32x4 acc[2][11] = {};
  const int rS = lane >> 2;
  const int cS = (lane & 3) * 8;
  const long baseRow = (long)blk * 128;

  for (int kk = 0; kk < FH; kk += 32) {
    for (int o = w; o < 11; o += 4)
      gld_lds16(Wxb + (o * 16 + rS) * FH + kk + cS, &lB[o * 16 * 32]);

    // A: load raw H, apply relu(a*h+c), ds_write
    f32x4 a0 = *(const f32x4*)&aL[kk + cS];
    f32x4 a1 = *(const f32x4*)&aL[kk + cS + 4];
    f32x4 c0 = *(const f32x4*)&cL[kk + cS];
    f32x4 c1 = *(const f32x4*)&cL[kk + cS + 4];
    #pragma unroll
    for (int c = 0; c < 2; ++c) {
      int chunk = 2 * w + c;
      uint4 raw = *(const uint4*)(Hraw + (baseRow + chunk * 16 + rS) * FH + kk + cS);
      unsigned short* u = (unsigned short*)&raw;
      #pragma unroll
      for (int j = 0; j < 4; ++j) {
        float v = bf2f(u[j]);
        u[j] = f2bf(fmaxf(a0[j] * v + c0[j], 0.f));
      }
      #pragma unroll
      for (int j = 0; j < 4; ++j) {
        float v = bf2f(u[4 + j]);
        u[4 + j] = f2bf(fmaxf(a1[j] * v + c1[j], 0.f));
      }
      *(uint4*)&lA[(chunk * 16 + rS) * 32 + cS] = raw;
    }
    __syncthreads();

    bf16x8 a8[2], b8[11];
    #pragma unroll
    for (int t = 0; t < 2; ++t)
      a8[t] = *(const bf16x8*)&lA[(w * 32 + t * 16 + (lane & 15)) * 32 + (lane >> 4) * 8];
    #pragma unroll
    for (int t = 0; t < 11; ++t)
      b8[t] = *(const bf16x8*)&lB[(t * 16 + (lane & 15)) * 32 + (lane >> 4) * 8];
    #pragma unroll
    for (int tm = 0; tm < 2; ++tm)
      #pragma unroll
      for (int tn = 0; tn < 11; ++tn)
        acc[tm][tn] = __builtin_amdgcn_mfma_f32_16x16x32_bf16(a8[tm], b8[tn], acc[tm][tn], 0, 0, 0);
    __syncthreads();
  }

  const int rowq = (lane >> 4) * 4;
  const int coll = lane & 15;
  const int g = blk * 4 + w;
  float psum = 0.f;
  #pragma unroll
  for (int tn = 0; tn < 11; ++tn) {
    int col = tn * 16 + coll;
    bool valid = col < NREAL;
    float bx = valid ? b_x[col] : 0.f;
    #pragma unroll
    for (int tm = 0; tm < 2; ++tm)
      #pragma unroll
      for (int r = 0; r < 4; ++r) {
        float p = valid ? expf(acc[tm][tn][r] + bx) : 0.f;
        acc[tm][tn][r] = p;
        psum += p;
      }
  }
  #pragma unroll
  for (int off = 32; off; off >>= 1) psum += __shfl_xor(psum, off);
  float Xe = Xxe[g];
  float inv = 1.0f / (psum + Xe);
  if (lane == 0) outE[g] = Xe * inv;

  #pragma unroll
  for (int tn = 0; tn < 11; ++tn) {
    int col = tn * 16 + coll;
    if (col >= NREAL) continue;
    #pragma unroll
    for (int tm = 0; tm < 2; ++tm)
      #pragma unroll
      for (int r = 0; r < 4; ++r) {
        long row = baseRow + w * 32 + tm * 16 + rowq + r;
        float v = acc[tm][tn][r] * inv;
        if (col >= 4) outA[row * 160 + (col - 4)] = v;
        else          outC[row * 4 + col] = v;
      }
  }
}

extern "C" void kernel_launch(void* const* d_in, const int* in_sizes, int n_in,
                              void* d_out, int out_size, void* d_ws, size_t ws_size,
                              hipStream_t stream)
{
  const float* X    = (const float*)d_in[0];
  const int*   NX   = (const int*)d_in[1];      // int64 in ref -> int32 in harness
  const float* W_h  = (const float*)d_in[3];
  const float* g_h  = (const float*)d_in[4];
  const float* b_h  = (const float*)d_in[5];
  const float* W_ht = (const float*)d_in[6];
  const float* g_ht = (const float*)d_in[7];
  const float* b_ht = (const float*)d_in[8];
  const float* W_x  = (const float*)d_in[9];
  const float* b_x  = (const float*)d_in[10];
  const float* W_xt = (const float*)d_in[11];
  const float* b_xt = (const float*)d_in[12];

  char* ws = (char*)d_ws;
  bf16*  X_endb= (bf16*)(ws + OFF_XENDB);
  bf16*  W1a   = (bf16*)(ws + OFF_W1A);
  bf16*  Bcat  = (bf16*)(ws + OFF_BCAT);
  bf16*  Wxb   = (bf16*)(ws + OFF_WXB);
  float* stats = (float*)(ws + OFF_STATS);
  float* s1m = stats, *s2m = stats + 512, *s1e = stats + 1024, *s2e = stats + 1536;
  float* Xxe   = (float*)(ws + OFF_XXE);
  float* Ccat  = (float*)(ws + OFF_CCAT);
  bf16*  H     = (bf16*)(ws + OFF_H);

  float* outA = (float*)d_out;                 // append: 131072*160
  float* outC = outA + (long)N_NODES * 160;    // connect: 131072*4
  float* outE = outC + (long)N_NODES * 4;      // end: 4096

  k_wcast<<<1024, 256, 0, stream>>>(W_h, W_ht, W_x, W1a, Bcat, Wxb, stats);
  k_xend<<<N_GRAPHS, 256, 0, stream>>>(X, NX, X_endb);
  gemm0<<<256, 256, 0, stream>>>(X_endb, Bcat, Ccat, s1e, s2e);
  k_xxend<<<1024, 256, 0, stream>>>(Ccat, s1e, s2e, g_ht, b_ht, W_xt, b_xt, Xxe);
  gemm1<<<4096, 256, 0, stream>>>(X, W1a, Ccat, H, s1m, s2m);
  gemm2<<<1024, 256, 0, stream>>>(H, Wxb, s1m, s2m, g_h, b_h, b_x, Xxe, outA, outC, outE);
}

// Round 4
// 403.083 us; speedup vs baseline: 1.1980x; 1.0607x over previous
//
#include <hip/hip_runtime.h>
#include <hip/hip_bf16.h>

typedef __hip_bfloat16 bf16;
typedef __attribute__((ext_vector_type(8))) short bf16x8;   // 8 bf16 = 4 VGPR
typedef __attribute__((ext_vector_type(4))) float f32x4;

#define N_NODES   131072
#define N_GRAPHS  4096
#define FIN       256
#define FH        512
#define NPAD      176     // 164 padded to 11*16
#define NREAL     164

// ---------- workspace layout (bytes) ----------
#define OFF_XB     0UL            // bf16 131072x256 = 67,108,864
#define OFF_XENDB  67108864UL     // bf16 4096x256   =  2,097,152
#define OFF_W1A    69206016UL     // bf16 512x256    =    262,144
#define OFF_BCAT   69468160UL     // bf16 1024x256   =    524,288
#define OFF_WXB    69992448UL     // bf16 176x512    =    180,224
#define OFF_STATS  70172672UL     // f32  4x512      =      8,192
#define OFF_XXE    70180864UL     // f32  4096
#define OFF_CCAT   70197248UL     // f32  4096x1024  = 16,777,216
#define OFF_H      86974464UL     // bf16 131072x512 = 134,217,728
// total ~211 MB

__device__ __forceinline__ void gld_lds16(const void* g, void* l) {
  __builtin_amdgcn_global_load_lds(
      (const __attribute__((address_space(1))) void*)g,
      (__attribute__((address_space(3))) void*)l, 16, 0, 0);
}

__device__ __forceinline__ float bf2f(unsigned short u) {
  unsigned int x = ((unsigned int)u) << 16; float f;
  __builtin_memcpy(&f, &x, 4); return f;
}
__device__ __forceinline__ unsigned short f2bf(float f) {
  bf16 h = __float2bfloat16(f); unsigned short u;
  __builtin_memcpy(&u, &h, 2); return u;
}

// ---------- K0: weight casts + zero stats ----------
__global__ __launch_bounds__(256) void k_wcast(
    const float* __restrict__ W_h, const float* __restrict__ W_ht,
    const float* __restrict__ W_x,
    bf16* __restrict__ W1a, bf16* __restrict__ Bcat, bf16* __restrict__ Wxb,
    float* __restrict__ stats)
{
  int i = blockIdx.x * 256 + threadIdx.x;            // grid 1024 -> 262144
  if (i < 2048) stats[i] = 0.f;                      // s1m,s2m,s1e,s2e
  if (i < 512 * 512) {
    int of = i >> 9, ic = i & 511;
    float v = W_h[i];
    if (ic < 256) W1a[of * 256 + ic] = __float2bfloat16(v);
    else          Bcat[of * 256 + (ic - 256)] = __float2bfloat16(v);
  }
  if (i < 512 * 256) Bcat[512 * 256 + i] = __float2bfloat16(W_ht[i]);
  if (i < NPAD * 512) {
    int n = i >> 9;
    Wxb[i] = (n < NREAL) ? __float2bfloat16(W_x[i]) : __float2bfloat16(0.f);
  }
}

// ---------- K1: per-graph mean of X + bf16 cast of X (fused) ----------
__global__ __launch_bounds__(256) void k_xend(
    const float* __restrict__ X, const int* __restrict__ NX,
    bf16* __restrict__ Xb, bf16* __restrict__ X_endb)
{
  int g = blockIdx.x;                 // 4096
  int t = threadIdx.x;
  int cg = t & 63;                    // cols cg*4..+3
  int rg = t >> 6;                    // rows rg*8..+7
  const float* Xg = X + (long)g * 32 * FIN;
  bf16* Xbg = Xb + (long)g * 32 * FIN;
  float4 s = {0.f, 0.f, 0.f, 0.f};
  #pragma unroll
  for (int r = 0; r < 8; ++r) {
    int off = (rg * 8 + r) * FIN + cg * 4;
    float4 v = *(const float4*)(Xg + off);
    s.x += v.x; s.y += v.y; s.z += v.z; s.w += v.w;
    ushort4 u = {f2bf(v.x), f2bf(v.y), f2bf(v.z), f2bf(v.w)};
    *(ushort4*)(Xbg + off) = u;
  }
  __shared__ float4 red[256];
  red[t] = s;
  __syncthreads();
  if (t < 64) {
    float4 a = red[t], b = red[t + 64], c = red[t + 128], d = red[t + 192];
    float inv = 1.f / (float)NX[g];
    float4 m = {(a.x + b.x + c.x + d.x) * inv, (a.y + b.y + c.y + d.y) * inv,
                (a.z + b.z + c.z + d.z) * inv, (a.w + b.w + c.w + d.w) * inv};
    ushort4 u = {f2bf(m.x), f2bf(m.y), f2bf(m.z), f2bf(m.w)};
    *(ushort4*)(X_endb + (long)g * FIN + t * 4) = u;
  }
}

// ---------- GEMM0: Ccat = X_endb @ [W1b; W_ht]^T  (M=4096,N=1024,K=256) ------
// + fused column stats for cols 512..1023 (the Hend half)
__global__ __launch_bounds__(256, 2) void gemm0(
    const bf16* __restrict__ A, const bf16* __restrict__ B,
    float* __restrict__ Cout, float* __restrict__ s1e, float* __restrict__ s2e)
{
  const int bid = blockIdx.x;                 // 256
  const int blkM = bid >> 3, blkN = bid & 7;
  const int tid = threadIdx.x;
  const int w = tid >> 6, lane = tid & 63;
  const int wm = w >> 1, wn = w & 1;

  __shared__ __align__(16) bf16 lA[128 * 32];
  __shared__ __align__(16) bf16 lB[128 * 32];
  __shared__ float sred[2][2][128];

  f32x4 acc[4][4] = {};
  const int rS = lane >> 2;
  const int cS = (lane & 3) * 8;
  const long baseA = (long)blkM * 128;
  const long baseB = (long)blkN * 128;

  for (int kk = 0; kk < FIN; kk += 32) {
    #pragma unroll
    for (int c = 0; c < 2; ++c) {
      int chunk = 2 * w + c;
      gld_lds16(A + (baseA + chunk * 16 + rS) * FIN + kk + cS, &lA[chunk * 16 * 32]);
      gld_lds16(B + (baseB + chunk * 16 + rS) * FIN + kk + cS, &lB[chunk * 16 * 32]);
    }
    __syncthreads();
    bf16x8 a8[4], b8[4];
    #pragma unroll
    for (int t = 0; t < 4; ++t) {
      a8[t] = *(const bf16x8*)&lA[(wm * 64 + t * 16 + (lane & 15)) * 32 + (lane >> 4) * 8];
      b8[t] = *(const bf16x8*)&lB[(wn * 64 + t * 16 + (lane & 15)) * 32 + (lane >> 4) * 8];
    }
    #pragma unroll
    for (int tm = 0; tm < 4; ++tm)
      #pragma unroll
      for (int tn = 0; tn < 4; ++tn)
        acc[tm][tn] = __builtin_amdgcn_mfma_f32_16x16x32_bf16(a8[tm], b8[tn], acc[tm][tn], 0, 0, 0);
    __syncthreads();
  }

  const int rowq = (lane >> 4) * 4;
  const int coll = lane & 15;
  float p1[4] = {0.f, 0.f, 0.f, 0.f}, p2[4] = {0.f, 0.f, 0.f, 0.f};
  #pragma unroll
  for (int tm = 0; tm < 4; ++tm)
    #pragma unroll
    for (int tn = 0; tn < 4; ++tn)
      #pragma unroll
      for (int r = 0; r < 4; ++r) {
        long row = baseA + wm * 64 + tm * 16 + rowq + r;
        int col = (int)baseB + wn * 64 + tn * 16 + coll;
        float v = acc[tm][tn][r];
        Cout[row * 1024 + col] = v;
        p1[tn] += v; p2[tn] += v * v;
      }

  if (blkN >= 4) {
    #pragma unroll
    for (int tn = 0; tn < 4; ++tn) {
      float q1 = p1[tn], q2 = p2[tn];
      q1 += __shfl_xor(q1, 16); q1 += __shfl_xor(q1, 32);
      q2 += __shfl_xor(q2, 16); q2 += __shfl_xor(q2, 32);
      if (lane < 16) {
        sred[wm][0][wn * 64 + tn * 16 + lane] = q1;
        sred[wm][1][wn * 64 + tn * 16 + lane] = q2;
      }
    }
    __syncthreads();
    int st = tid >> 7, c = tid & 127;
    float v = sred[0][st][c] + sred[1][st][c];
    atomicAdd((st ? s2e : s1e) + (blkN - 4) * 128 + c, v);
  }
}

// ---------- K3: end path, folded finalize ----------
__global__ __launch_bounds__(256) void k_xxend(
    const float* __restrict__ Ccat, const float* __restrict__ s1e,
    const float* __restrict__ s2e, const float* __restrict__ g_ht,
    const float* __restrict__ b_ht, const float* __restrict__ Wxt,
    const float* __restrict__ bxt, float* __restrict__ Xxe)
{
  __shared__ float aL[512], cL[512];
  int tid = threadIdx.x;
  #pragma unroll
  for (int i = tid; i < 512; i += 256) {
    float mean = s1e[i] * 2.44140625e-4f;
    float var = s2e[i] * 2.44140625e-4f - mean * mean;
    float a = g_ht[i] / sqrtf(var + 1e-5f);
    aL[i] = a; cL[i] = b_ht[i] - mean * a;
  }
  __syncthreads();
  int w = tid >> 6, lane = tid & 63;
  int g = blockIdx.x * 4 + w;          // grid 1024
  const float* h = Ccat + (long)g * 1024 + 512;
  float acc = 0.f;
  #pragma unroll
  for (int i = 0; i < 8; ++i) {
    int j = lane + i * 64;
    float x = fmaxf(aL[j] * h[j] + cL[j], 0.f);
    acc += x * Wxt[j];
  }
  #pragma unroll
  for (int off = 32; off; off >>= 1) acc += __shfl_xor(acc, off);
  if (lane == 0) Xxe[g] = expf(acc + bxt[0]);
}

// ---------- GEMM1: H = bf16(Xb @ W1a^T + Bterm[graph]) + fused stats ----------
// M-tile 64 rows (2 graphs), ALL 512 cols per block -> Xb read exactly once.
// 4 waves, wave-tile 64x128 (wave w owns cols w*128..+127), acc 4x8 f32x4.
__global__ __launch_bounds__(256, 2) void gemm1(
    const bf16* __restrict__ Xb, const bf16* __restrict__ W1a,
    const float* __restrict__ Ccat, bf16* __restrict__ H,
    float* __restrict__ s1m, float* __restrict__ s2m)
{
  const int bid = blockIdx.x;          // 2048
  const int tid = threadIdx.x;
  const int w = tid >> 6, lane = tid & 63;

  __shared__ __align__(16) bf16 lA[64 * 32];
  __shared__ __align__(16) bf16 lB[512 * 32];

  f32x4 acc[4][8] = {};
  const int rS = lane >> 2;
  const int cS = (lane & 3) * 8;
  const long baseA = (long)bid * 64;

  for (int kk = 0; kk < FIN; kk += 32) {
    gld_lds16(Xb + (baseA + w * 16 + rS) * FIN + kk + cS, &lA[w * 16 * 32]);
    #pragma unroll
    for (int o = 0; o < 8; ++o) {
      int chunk = o * 4 + w;           // 32 chunks of 16 rows of W1a
      gld_lds16(W1a + (chunk * 16 + rS) * FIN + kk + cS, &lB[chunk * 16 * 32]);
    }
    __syncthreads();
    bf16x8 a8[4], b8[8];
    #pragma unroll
    for (int t = 0; t < 4; ++t)
      a8[t] = *(const bf16x8*)&lA[(t * 16 + (lane & 15)) * 32 + (lane >> 4) * 8];
    #pragma unroll
    for (int j = 0; j < 8; ++j)
      b8[j] = *(const bf16x8*)&lB[(w * 128 + j * 16 + (lane & 15)) * 32 + (lane >> 4) * 8];
    #pragma unroll
    for (int t = 0; t < 4; ++t)
      #pragma unroll
      for (int j = 0; j < 8; ++j)
        acc[t][j] = __builtin_amdgcn_mfma_f32_16x16x32_bf16(a8[t], b8[j], acc[t][j], 0, 0, 0);
    __syncthreads();
  }

  const int q4 = (lane >> 4) * 4;      // C/D: col=lane&15, row=(lane>>4)*4+reg
  const int coll = lane & 15;
  // Bterm for the 2 graphs of this block, 8 col-tiles
  float ct[2][8];
  #pragma unroll
  for (int a = 0; a < 2; ++a)
    #pragma unroll
    for (int j = 0; j < 8; ++j)
      ct[a][j] = Ccat[(long)(bid * 2 + a) * 1024 + w * 128 + j * 16 + coll];

  float p1[8], p2[8];
  #pragma unroll
  for (int j = 0; j < 8; ++j) { p1[j] = 0.f; p2[j] = 0.f; }

  #pragma unroll
  for (int t = 0; t < 4; ++t)
    #pragma unroll
    for (int j = 0; j < 8; ++j)
      #pragma unroll
      for (int r = 0; r < 4; ++r) {
        long row = baseA + t * 16 + q4 + r;
        int col = w * 128 + j * 16 + coll;
        float h = acc[t][j][r] + ct[t >> 1][j];
        H[row * FH + col] = __float2bfloat16(h);
        p1[j] += h; p2[j] += h * h;
      }

  #pragma unroll
  for (int j = 0; j < 8; ++j) {
    float q1 = p1[j], q2 = p2[j];
    q1 += __shfl_xor(q1, 16); q1 += __shfl_xor(q1, 32);
    q2 += __shfl_xor(q2, 16); q2 += __shfl_xor(q2, 32);
    if (lane < 16) {
      atomicAdd(s1m + w * 128 + j * 16 + lane, q1);
      atomicAdd(s2m + w * 128 + j * 16 + lane, q2);
    }
  }
}

// ---------- GEMM2: fused BN-finalize + relu-transform + exp/graph-softmax ----
__global__ __launch_bounds__(256, 2) void gemm2(
    const bf16* __restrict__ Hraw, const bf16* __restrict__ Wxb,
    const float* __restrict__ s1m, const float* __restrict__ s2m,
    const float* __restrict__ g_h, const float* __restrict__ b_h,
    const float* __restrict__ b_x, const float* __restrict__ Xxe,
    float* __restrict__ outA, float* __restrict__ outC, float* __restrict__ outE)
{
  const int blk = blockIdx.x;          // 1024
  const int tid = threadIdx.x;
  const int w = tid >> 6, lane = tid & 63;

  __shared__ __align__(16) bf16 lA[128 * 32];
  __shared__ __align__(16) bf16 lB[NPAD * 32];
  __shared__ float aL[512], cL[512];

  #pragma unroll
  for (int i = tid; i < 512; i += 256) {
    float mean = s1m[i] * 7.62939453125e-6f;
    float var = s2m[i] * 7.62939453125e-6f - mean * mean;
    float a = g_h[i] / sqrtf(var + 1e-5f);
    aL[i] = a; cL[i] = b_h[i] - mean * a;
  }
  __syncthreads();

  f32x4 acc[2][11] = {};
  const int rS = lane >> 2;
  const int cS = (lane & 3) * 8;
  const long baseRow = (long)blk * 128;

  for (int kk = 0; kk < FH; kk += 32) {
    for (int o = w; o < 11; o += 4)
      gld_lds16(Wxb + (o * 16 + rS) * FH + kk + cS, &lB[o * 16 * 32]);

    // A: load raw H, apply relu(a*h+c), ds_write
    f32x4 a0 = *(const f32x4*)&aL[kk + cS];
    f32x4 a1 = *(const f32x4*)&aL[kk + cS + 4];
    f32x4 c0 = *(const f32x4*)&cL[kk + cS];
    f32x4 c1 = *(const f32x4*)&cL[kk + cS + 4];
    #pragma unroll
    for (int c = 0; c < 2; ++c) {
      int chunk = 2 * w + c;
      uint4 raw = *(const uint4*)(Hraw + (baseRow + chunk * 16 + rS) * FH + kk + cS);
      unsigned short* u = (unsigned short*)&raw;
      #pragma unroll
      for (int j = 0; j < 4; ++j) {
        float v = bf2f(u[j]);
        u[j] = f2bf(fmaxf(a0[j] * v + c0[j], 0.f));
      }
      #pragma unroll
      for (int j = 0; j < 4; ++j) {
        float v = bf2f(u[4 + j]);
        u[4 + j] = f2bf(fmaxf(a1[j] * v + c1[j], 0.f));
      }
      *(uint4*)&lA[(chunk * 16 + rS) * 32 + cS] = raw;
    }
    __syncthreads();

    bf16x8 a8[2], b8[11];
    #pragma unroll
    for (int t = 0; t < 2; ++t)
      a8[t] = *(const bf16x8*)&lA[(w * 32 + t * 16 + (lane & 15)) * 32 + (lane >> 4) * 8];
    #pragma unroll
    for (int t = 0; t < 11; ++t)
      b8[t] = *(const bf16x8*)&lB[(t * 16 + (lane & 15)) * 32 + (lane >> 4) * 8];
    #pragma unroll
    for (int tm = 0; tm < 2; ++tm)
      #pragma unroll
      for (int tn = 0; tn < 11; ++tn)
        acc[tm][tn] = __builtin_amdgcn_mfma_f32_16x16x32_bf16(a8[tm], b8[tn], acc[tm][tn], 0, 0, 0);
    __syncthreads();
  }

  const int rowq = (lane >> 4) * 4;
  const int coll = lane & 15;
  const int g = blk * 4 + w;
  float psum = 0.f;
  #pragma unroll
  for (int tn = 0; tn < 11; ++tn) {
    int col = tn * 16 + coll;
    bool valid = col < NREAL;
    float bx = valid ? b_x[col] : 0.f;
    #pragma unroll
    for (int tm = 0; tm < 2; ++tm)
      #pragma unroll
      for (int r = 0; r < 4; ++r) {
        float p = valid ? expf(acc[tm][tn][r] + bx) : 0.f;
        acc[tm][tn][r] = p;
        psum += p;
      }
  }
  #pragma unroll
  for (int off = 32; off; off >>= 1) psum += __shfl_xor(psum, off);
  float Xe = Xxe[g];
  float inv = 1.0f / (psum + Xe);
  if (lane == 0) outE[g] = Xe * inv;

  #pragma unroll
  for (int tn = 0; tn < 11; ++tn) {
    int col = tn * 16 + coll;
    if (col >= NREAL) continue;
    #pragma unroll
    for (int tm = 0; tm < 2; ++tm)
      #pragma unroll
      for (int r = 0; r < 4; ++r) {
        long row = baseRow + w * 32 + tm * 16 + rowq + r;
        float v = acc[tm][tn][r] * inv;
        if (col >= 4) outA[row * 160 + (col - 4)] = v;
        else          outC[row * 4 + col] = v;
      }
  }
}

extern "C" void kernel_launch(void* const* d_in, const int* in_sizes, int n_in,
                              void* d_out, int out_size, void* d_ws, size_t ws_size,
                              hipStream_t stream)
{
  const float* X    = (const float*)d_in[0];
  const int*   NX   = (const int*)d_in[1];      // int64 in ref -> int32 in harness
  const float* W_h  = (const float*)d_in[3];
  const float* g_h  = (const float*)d_in[4];
  const float* b_h  = (const float*)d_in[5];
  const float* W_ht = (const float*)d_in[6];
  const float* g_ht = (const float*)d_in[7];
  const float* b_ht = (const float*)d_in[8];
  const float* W_x  = (const float*)d_in[9];
  const float* b_x  = (const float*)d_in[10];
  const float* W_xt = (const float*)d_in[11];
  const float* b_xt = (const float*)d_in[12];

  char* ws = (char*)d_ws;
  bf16*  Xb    = (bf16*)(ws + OFF_XB);
  bf16*  X_endb= (bf16*)(ws + OFF_XENDB);
  bf16*  W1a   = (bf16*)(ws + OFF_W1A);
  bf16*  Bcat  = (bf16*)(ws + OFF_BCAT);
  bf16*  Wxb   = (bf16*)(ws + OFF_WXB);
  float* stats = (float*)(ws + OFF_STATS);
  float* s1m = stats, *s2m = stats + 512, *s1e = stats + 1024, *s2e = stats + 1536;
  float* Xxe   = (float*)(ws + OFF_XXE);
  float* Ccat  = (float*)(ws + OFF_CCAT);
  bf16*  H     = (bf16*)(ws + OFF_H);

  float* outA = (float*)d_out;                 // append: 131072*160
  float* outC = outA + (long)N_NODES * 160;    // connect: 131072*4
  float* outE = outC + (long)N_NODES * 4;      // end: 4096

  k_wcast<<<1024, 256, 0, stream>>>(W_h, W_ht, W_x, W1a, Bcat, Wxb, stats);
  k_xend<<<N_GRAPHS, 256, 0, stream>>>(X, NX, Xb, X_endb);
  gemm0<<<256, 256, 0, stream>>>(X_endb, Bcat, Ccat, s1e, s2e);
  k_xxend<<<1024, 256, 0, stream>>>(Ccat, s1e, s2e, g_ht, b_ht, W_xt, b_xt, Xxe);
  gemm1<<<2048, 256, 0, stream>>>(Xb, W1a, Ccat, H, s1m, s2m);
  gemm2<<<1024, 256, 0, stream>>>(H, Wxb, s1m, s2m, g_h, b_h, b_x, Xxe, outA, outC, outE);
}